// Round 1
// baseline (377.075 us; speedup 1.0000x reference)
//
#include <hip/hip_runtime.h>

// Problem dims (fixed by reference setup_inputs)
constexpr int B = 64, T = 256, I = 2048, H = 4096, O = 1024;

#define DECAY 0.9f
#define THRESH 1.0f

// ---------------------------------------------------------------------------
// Kernel 1: xbar[t,i] = (1/B) * sum_b x[b,t,i]   (float4 vectorized, coalesced)
// x: [B,T,I] fp32 (134 MB). One thread per float4 of the [T,I] plane.
// ---------------------------------------------------------------------------
__global__ __launch_bounds__(256) void batch_reduce(const float* __restrict__ x,
                                                    float* __restrict__ xbar) {
    const int idx = blockIdx.x * blockDim.x + threadIdx.x;  // float4 index in [T*I/4)
    const float4* x4 = (const float4*)x;
    const int stride4 = (T * I) / 4;  // per-batch stride in float4s
    float4 acc = {0.f, 0.f, 0.f, 0.f};
#pragma unroll 8
    for (int b = 0; b < B; ++b) {
        float4 v = x4[idx + b * stride4];
        acc.x += v.x; acc.y += v.y; acc.z += v.z; acc.w += v.w;
    }
    const float s = 1.0f / (float)B;
    acc.x *= s; acc.y *= s; acc.z *= s; acc.w *= s;
    ((float4*)xbar)[idx] = acc;
}

// ---------------------------------------------------------------------------
// Kernel 2: currents[t,h] = xbar[t,:] @ W_in[:,h] + b_in[h]
// fp32 tiled GEMM (no fp32 MFMA on CDNA4 -> vector ALU).
// M=256(T), N=4096(H), K=2048(I). BM=BN=64, BK=16, 256 thr, 4x4 per thread.
// ---------------------------------------------------------------------------
#define BM 64
#define BN 64
#define BK 16
#define LDA_PAD 4   // pad inner dim to 68 floats: keeps 16B alignment, 2-way banks (free)

__global__ __launch_bounds__(256) void gemm_in(const float* __restrict__ A,   // [T,I]
                                               const float* __restrict__ Bw,  // [I,H]
                                               const float* __restrict__ bias,// [H]
                                               float* __restrict__ C) {       // [T,H]
    __shared__ float As[BK][BM + LDA_PAD];  // stored transposed: As[k][m]
    __shared__ float Bs[BK][BN + LDA_PAD];  // Bs[k][n]

    const int tid = threadIdx.x;
    const int blockRow = blockIdx.y * BM;   // over T
    const int blockCol = blockIdx.x * BN;   // over H

    const int tr = tid >> 4;                // 0..15 -> rows tr*4..tr*4+3
    const int tc = tid & 15;                // 0..15 -> cols tc*4..tc*4+3

    // A tile load mapping: 64x16 floats, one float4 per thread
    const int aRow = tid >> 2;              // 0..63
    const int aCol = (tid & 3) << 2;        // 0,4,8,12
    // B tile load mapping: 16x64 floats, one float4 per thread
    const int bRow = tid >> 4;              // 0..15
    const int bCol = (tid & 15) << 2;       // 0..60

    float acc[4][4];
#pragma unroll
    for (int i = 0; i < 4; ++i)
#pragma unroll
        for (int j = 0; j < 4; ++j) acc[i][j] = 0.f;

    for (int k0 = 0; k0 < I; k0 += BK) {
        float4 av = *(const float4*)(&A[(blockRow + aRow) * I + k0 + aCol]);
        float4 bv = *(const float4*)(&Bw[(size_t)(k0 + bRow) * H + blockCol + bCol]);
        __syncthreads();  // protect LDS from previous iteration's readers
        As[aCol + 0][aRow] = av.x;
        As[aCol + 1][aRow] = av.y;
        As[aCol + 2][aRow] = av.z;
        As[aCol + 3][aRow] = av.w;
        *(float4*)(&Bs[bRow][bCol]) = bv;
        __syncthreads();

#pragma unroll
        for (int k = 0; k < BK; ++k) {
            float4 a = *(const float4*)(&As[k][tr << 2]);
            float4 b = *(const float4*)(&Bs[k][tc << 2]);
            const float ar[4] = {a.x, a.y, a.z, a.w};
            const float br[4] = {b.x, b.y, b.z, b.w};
#pragma unroll
            for (int i = 0; i < 4; ++i)
#pragma unroll
                for (int j = 0; j < 4; ++j) acc[i][j] += ar[i] * br[j];
        }
    }

    // epilogue: add bias, float4 stores
    const float4 bb = *(const float4*)(&bias[blockCol + (tc << 2)]);
    const float bbr[4] = {bb.x, bb.y, bb.z, bb.w};
#pragma unroll
    for (int i = 0; i < 4; ++i) {
        const int row = blockRow + (tr << 2) + i;
        float4 o;
        o.x = acc[i][0] + bbr[0];
        o.y = acc[i][1] + bbr[1];
        o.z = acc[i][2] + bbr[2];
        o.w = acc[i][3] + bbr[3];
        *(float4*)(&C[(size_t)row * H + blockCol + (tc << 2)]) = o;
    }
}

// ---------------------------------------------------------------------------
// Kernel 3: leaky integrate-and-fire scan over T per neuron h.
// One thread per h; t-loop unrolled x8 so 8 loads are in flight (addresses
// independent of the sequential m recurrence).
// ---------------------------------------------------------------------------
__global__ __launch_bounds__(64) void lif_scan(const float* __restrict__ cur, // [T,H]
                                               const float* __restrict__ m0,  // [H]
                                               float* __restrict__ agg) {     // [H]
    const int h = blockIdx.x * 64 + threadIdx.x;
    float m = m0[h];
    float count = 0.f;
    for (int t = 0; t < T; t += 8) {
        float c[8];
#pragma unroll
        for (int j = 0; j < 8; ++j) c[j] = cur[(size_t)(t + j) * H + h];
#pragma unroll
        for (int j = 0; j < 8; ++j) {
            m = DECAY * m + c[j];
            if (m > THRESH) { count += 1.f; m = 0.f; }
        }
    }
    agg[h] = count * (1.0f / (float)T);
}

// ---------------------------------------------------------------------------
// Kernel 4a: out[o] = b_out[o]  (d_out is poisoned 0xAA before every launch)
// Kernel 4b: out[o] += sum_{h in chunk} agg[h] * W_out[h,o]  via fp32 atomics
// ---------------------------------------------------------------------------
__global__ __launch_bounds__(256) void out_init(const float* __restrict__ b_out,
                                                float* __restrict__ out) {
    const int o = blockIdx.x * 256 + threadIdx.x;
    out[o] = b_out[o];
}

__global__ __launch_bounds__(256) void out_gemv(const float* __restrict__ agg,
                                                const float* __restrict__ Wout, // [H,O]
                                                float* __restrict__ out) {
    const int o = blockIdx.x * 256 + threadIdx.x;
    const int h0 = blockIdx.y * 128;
    float s = 0.f;
#pragma unroll 8
    for (int h = h0; h < h0 + 128; ++h) {
        s += agg[h] * Wout[(size_t)h * O + o];
    }
    atomicAdd(&out[o], s);
}

// ---------------------------------------------------------------------------
extern "C" void kernel_launch(void* const* d_in, const int* in_sizes, int n_in,
                              void* d_out, int out_size, void* d_ws, size_t ws_size,
                              hipStream_t stream) {
    const float* x     = (const float*)d_in[0];
    const float* W_in  = (const float*)d_in[1];
    const float* b_in  = (const float*)d_in[2];
    const float* W_out = (const float*)d_in[3];
    const float* b_out = (const float*)d_in[4];
    const float* m0    = (const float*)d_in[5];
    float* out = (float*)d_out;

    // workspace layout (fp32): xbar [T*I] | currents [T*H] | agg [H]
    float* xbar     = (float*)d_ws;
    float* currents = xbar + (size_t)T * I;
    float* agg      = currents + (size_t)T * H;

    // 1) batch-mean of x over B: 134 MB read, memory-bound
    batch_reduce<<<(T * I / 4) / 256, 256, 0, stream>>>(x, xbar);

    // 2) currents = xbar @ W_in + b_in  (fp32 vector GEMM)
    dim3 g2(H / BN, T / BM);
    gemm_in<<<g2, 256, 0, stream>>>(xbar, W_in, b_in, currents);

    // 3) LIF scan over T -> agg[h]
    lif_scan<<<H / 64, 64, 0, stream>>>(currents, m0, agg);

    // 4) out = agg @ W_out + b_out
    out_init<<<O / 256, 256, 0, stream>>>(b_out, out);
    dim3 g4(O / 256, H / 128);
    out_gemv<<<g4, 256, 0, stream>>>(agg, W_out, out);
}

// Round 2
// 331.742 us; speedup vs baseline: 1.1366x; 1.1366x over previous
//
#include <hip/hip_runtime.h>

// Problem dims (fixed by reference setup_inputs)
constexpr int B = 64, T = 256, I = 2048, H = 4096, O = 1024;

#define DECAY 0.9f
#define THRESH 1.0f

// ---------------------------------------------------------------------------
// Kernel 1: xbar[t,i] = (1/B) * sum_b x[b,t,i]   (float4, coalesced, unroll 16)
// 134 MB read -> memory-bound floor ~21 us.
// ---------------------------------------------------------------------------
__global__ __launch_bounds__(256) void batch_reduce(const float* __restrict__ x,
                                                    float* __restrict__ xbar) {
    const int idx = blockIdx.x * 256 + threadIdx.x;  // float4 index in [T*I/4)
    const float4* x4 = (const float4*)x;
    const int stride4 = (T * I) / 4;  // per-batch stride in float4s
    float4 acc = {0.f, 0.f, 0.f, 0.f};
#pragma unroll 16
    for (int b = 0; b < B; ++b) {
        float4 v = x4[idx + b * stride4];
        acc.x += v.x; acc.y += v.y; acc.z += v.z; acc.w += v.w;
    }
    const float s = 1.0f / (float)B;
    acc.x *= s; acc.y *= s; acc.z *= s; acc.w *= s;
    ((float4*)xbar)[idx] = acc;
}

// ---------------------------------------------------------------------------
// Kernel 2a: currents[t,h] = b_in[h]   (accumulation base for split-K atomics)
// ---------------------------------------------------------------------------
__global__ __launch_bounds__(256) void cur_init(const float* __restrict__ b_in,
                                                float* __restrict__ cur) {
    const int idx = blockIdx.x * 256 + threadIdx.x;   // float4 index over T*H/4
    const int h4 = idx & (H / 4 - 1);
    ((float4*)cur)[idx] = ((const float4*)b_in)[h4];
}

// ---------------------------------------------------------------------------
// Kernel 2b: currents[t,h] += xbar[t,:] @ W_in[:,h]   split-K fp32 GEMM
// M=256(T), N=4096(H), K=2048(I). BM=BN=64, BK=16, 256 thr, 4x4/thread.
// Split-K=4 -> 1024 blocks = 4 blocks/CU = 16 waves/CU (occupancy fix).
// Epilogue: fp32 atomicAdd (4-way contention per address only).
// ---------------------------------------------------------------------------
#define BM 64
#define BN 64
#define BK 16
#define KSPLIT 4
#define LDS_PAD 4

__global__ __launch_bounds__(256) void gemm_in(const float* __restrict__ A,   // [T,I]
                                               const float* __restrict__ Bw,  // [I,H]
                                               float* __restrict__ C) {       // [T,H]
    __shared__ float As[BK][BM + LDS_PAD];  // As[k][m]
    __shared__ float Bs[BK][BN + LDS_PAD];  // Bs[k][n]

    const int tid = threadIdx.x;
    const int blockRow = blockIdx.y * BM;   // over T
    const int blockCol = blockIdx.x * BN;   // over H
    const int kBeg = blockIdx.z * (I / KSPLIT);
    const int kEnd = kBeg + (I / KSPLIT);

    const int tr = tid >> 4;                // 0..15 -> rows tr*4..tr*4+3
    const int tc = tid & 15;                // 0..15 -> cols tc*4..tc*4+3

    const int aRow = tid >> 2;              // 0..63
    const int aCol = (tid & 3) << 2;        // 0,4,8,12
    const int bRow = tid >> 4;              // 0..15
    const int bCol = (tid & 15) << 2;       // 0..60

    float acc[4][4];
#pragma unroll
    for (int i = 0; i < 4; ++i)
#pragma unroll
        for (int j = 0; j < 4; ++j) acc[i][j] = 0.f;

    for (int k0 = kBeg; k0 < kEnd; k0 += BK) {
        float4 av = *(const float4*)(&A[(blockRow + aRow) * I + k0 + aCol]);
        float4 bv = *(const float4*)(&Bw[(size_t)(k0 + bRow) * H + blockCol + bCol]);
        __syncthreads();  // protect LDS from previous iteration's readers
        As[aCol + 0][aRow] = av.x;
        As[aCol + 1][aRow] = av.y;
        As[aCol + 2][aRow] = av.z;
        As[aCol + 3][aRow] = av.w;
        *(float4*)(&Bs[bRow][bCol]) = bv;
        __syncthreads();

#pragma unroll
        for (int k = 0; k < BK; ++k) {
            float4 a = *(const float4*)(&As[k][tr << 2]);
            float4 b = *(const float4*)(&Bs[k][tc << 2]);
            const float ar[4] = {a.x, a.y, a.z, a.w};
            const float br[4] = {b.x, b.y, b.z, b.w};
#pragma unroll
            for (int i = 0; i < 4; ++i)
#pragma unroll
                for (int j = 0; j < 4; ++j) acc[i][j] += ar[i] * br[j];
        }
    }

#pragma unroll
    for (int i = 0; i < 4; ++i) {
        const int row = blockRow + (tr << 2) + i;
#pragma unroll
        for (int j = 0; j < 4; ++j) {
            atomicAdd(&C[(size_t)row * H + blockCol + (tc << 2) + j], acc[i][j]);
        }
    }
}

// ---------------------------------------------------------------------------
// Kernel 3: leaky integrate-and-fire scan over T per neuron h.
// One thread per h; unroll 16 keeps 16 loads in flight per thread.
// ---------------------------------------------------------------------------
__global__ __launch_bounds__(256) void lif_scan(const float* __restrict__ cur, // [T,H]
                                                const float* __restrict__ m0,  // [H]
                                                float* __restrict__ agg) {     // [H]
    const int h = blockIdx.x * 256 + threadIdx.x;
    float m = m0[h];
    float count = 0.f;
    for (int t = 0; t < T; t += 16) {
        float c[16];
#pragma unroll
        for (int j = 0; j < 16; ++j) c[j] = cur[(size_t)(t + j) * H + h];
#pragma unroll
        for (int j = 0; j < 16; ++j) {
            m = DECAY * m + c[j];
            if (m > THRESH) { count += 1.f; m = 0.f; }
        }
    }
    agg[h] = count * (1.0f / (float)T);
}

// ---------------------------------------------------------------------------
// Kernel 4a: out[o] = b_out[o]  (d_out is poisoned 0xAA before every launch)
// Kernel 4b: out[o] += sum_{h in chunk} agg[h] * W_out[h,o]  via fp32 atomics
// ---------------------------------------------------------------------------
__global__ __launch_bounds__(256) void out_init(const float* __restrict__ b_out,
                                                float* __restrict__ out) {
    const int o = blockIdx.x * 256 + threadIdx.x;
    out[o] = b_out[o];
}

__global__ __launch_bounds__(256) void out_gemv(const float* __restrict__ agg,
                                                const float* __restrict__ Wout, // [H,O]
                                                float* __restrict__ out) {
    const int o = blockIdx.x * 256 + threadIdx.x;
    const int h0 = blockIdx.y * 128;
    float s = 0.f;
#pragma unroll 8
    for (int h = h0; h < h0 + 128; ++h) {
        s += agg[h] * Wout[(size_t)h * O + o];
    }
    atomicAdd(&out[o], s);
}

// ---------------------------------------------------------------------------
extern "C" void kernel_launch(void* const* d_in, const int* in_sizes, int n_in,
                              void* d_out, int out_size, void* d_ws, size_t ws_size,
                              hipStream_t stream) {
    const float* x     = (const float*)d_in[0];
    const float* W_in  = (const float*)d_in[1];
    const float* b_in  = (const float*)d_in[2];
    const float* W_out = (const float*)d_in[3];
    const float* b_out = (const float*)d_in[4];
    const float* m0    = (const float*)d_in[5];
    float* out = (float*)d_out;

    // workspace layout (fp32): xbar [T*I] | currents [T*H] | agg [H]
    float* xbar     = (float*)d_ws;
    float* currents = xbar + (size_t)T * I;
    float* agg      = currents + (size_t)T * H;

    // 1) batch-mean of x over B: 134 MB read, memory-bound
    batch_reduce<<<(T * I / 4) / 256, 256, 0, stream>>>(x, xbar);

    // 2a) currents = b_in (broadcast) -- base for split-K atomic accumulation
    cur_init<<<(T * H / 4) / 256, 256, 0, stream>>>(b_in, currents);

    // 2b) currents += xbar @ W_in  (split-K=4 fp32 vector GEMM, 1024 blocks)
    dim3 g2(H / BN, T / BM, KSPLIT);
    gemm_in<<<g2, 256, 0, stream>>>(xbar, W_in, currents);

    // 3) LIF scan over T -> agg[h]
    lif_scan<<<H / 256, 256, 0, stream>>>(currents, m0, agg);

    // 4) out = agg @ W_out + b_out
    out_init<<<O / 256, 256, 0, stream>>>(b_out, out);
    dim3 g4(O / 256, H / 128);
    out_gemv<<<g4, 256, 0, stream>>>(agg, W_out, out);
}